// Round 7
// baseline (345.649 us; speedup 1.0000x reference)
//
#include <hip/hip_runtime.h>
#include <stdint.h>

typedef unsigned short u16;
typedef __attribute__((ext_vector_type(4))) float f32x4;
typedef __attribute__((ext_vector_type(8))) short bf16x8;
typedef __attribute__((ext_vector_type(8))) u16 u16x8;

#define T_SEQ  2048
#define EMB    2048
#define HD     128
#define NHEAD  16
#define NTOK   4096
#define NE3    6144
#define SCALE  0.29730177875068026f   // 128^-0.25
#define LOG2E  1.44269504088896f

typedef __attribute__((address_space(3))) char* lds_t;
typedef const __attribute__((address_space(1))) char* gl_t;

__device__ __forceinline__ void gld16(const void* g, void* l) {
  __builtin_amdgcn_global_load_lds((gl_t)g, (lds_t)l, 16, 0, 0);
}

__device__ __forceinline__ u16 f2bf(float f) {
  union { float f; uint32_t u; } c; c.f = f;
  uint32_t r = c.u + 0x7fffu + ((c.u >> 16) & 1u);
  return (u16)(r >> 16);
}

// ---------------- fp32 -> bf16 conversion (memory-bound) ----------------
__global__ __launch_bounds__(256) void cvt_bf16(const float* __restrict__ in,
                                                u16* __restrict__ out, int n8) {
  int i = blockIdx.x * 256 + threadIdx.x;
  if (i >= n8) return;
  const float4* p = (const float4*)in + (size_t)i * 2;
  float4 a = p[0], b = p[1];
  u16x8 o;
  o[0]=f2bf(a.x); o[1]=f2bf(a.y); o[2]=f2bf(a.z); o[3]=f2bf(a.w);
  o[4]=f2bf(b.x); o[5]=f2bf(b.y); o[6]=f2bf(b.z); o[7]=f2bf(b.w);
  *((u16x8*)out + i) = o;
}

// ======== 128x256 bf16 GEMM, wave tile 128x64 (4 waves), B^T layout ========
// C[m][n] = sum_k A[m][k]*Bm[n][k].  256 threads, wave w owns cols w*64..+63,
// all 128 rows (acc[8][4]).  Arithmetic intensity 42.7 FLOP/LDS-byte (vs 32
// for 64x64 tiles) -> LDS read BW no longer caps MFMA below ~95%.
// LDS: 3 slots x (A 8KB + B 16KB) = 72KB -> 2 blocks/CU, cross-block overlap.
// Depth-2 pipeline, uniform gate vmcnt(6) (pairs q,q+1 in flight = 12 loads;
// wait until 6 -> pair q landed).  Slot rows 64B with col' = c ^ ((row>>1)&3)
// involution (read and staged global source use the same XOR) -> 2-way max.
// Supertile: block i -> r=i>>8, x=i&7 (XCD), s=(i>>3)&31; regionId=r*8+x;
// 32-block compact 8bMx4bN region per XCD streams A+B K-lockstep via its L2.

__device__ __forceinline__ bf16x8 rdfrag(const char* slot, int row, int lq) {
  return *(const bf16x8*)(slot + row*64 + ((lq ^ ((row >> 1) & 3)) << 4));
}
// stage one 4KB round (256 thr x 16B) into row-major [rows][32k] slot
__device__ __forceinline__ void stg(const char* g, int K2, int kb,
                                    char* slot, int j, int tid) {
  int lb = j*4096 + tid*16;
  int row = lb >> 6, c = (lb >> 4) & 3;
  gld16(g + (size_t)row*K2 + kb + ((c ^ ((row >> 1) & 3)) << 4), slot + lb);
}

template<int EPI, int NBN>
__global__ __launch_bounds__(256, 2) void gemmW(
    const u16* __restrict__ A, const u16* __restrict__ Bm, int K, int N,
    const float* __restrict__ cosT, const float* __restrict__ sinT,
    const float* __restrict__ bias,
    u16* __restrict__ Qh, u16* __restrict__ Kh, u16* __restrict__ Vt,
    float* __restrict__ Cout)
{
  __shared__ __align__(16) char lds[73728];   // A slots 0..24575, B 24576..
  const int tid = threadIdx.x;
  const int lane = tid & 63, wn = tid >> 6;   // 4 waves, 1M x 4N
  const int l15 = lane & 15, lq = lane >> 4;

  // supertile decode (bijective for grids 768 and 256)
  const int i = blockIdx.x;
  const int r = i >> 8, x = i & 7, s = (i >> 3) & 31;
  const int regionId = r*8 + x;
  const int RM = regionId & 3, RN = regionId >> 2;
  const int bM = RM*8 + (s >> 2);
  const int bN = RN*4 + (s & 3);

  const char* Ag = (const char*)(A + (size_t)bM * 128 * K);
  const char* Bg = (const char*)(Bm + (size_t)bN * 256 * K);
  const int K2 = K * 2;
  const int nQ = K >> 5;          // phases of K=32

  // prologue: stage pairs 0,1 into slots 0,1 (6 loads each)
  #pragma unroll
  for (int q = 0; q < 2; ++q) {
    stg(Ag, K2, q*64, lds + q*8192, 0, tid);
    stg(Ag, K2, q*64, lds + q*8192, 1, tid);
    stg(Bg, K2, q*64, lds + 24576 + q*16384, 0, tid);
    stg(Bg, K2, q*64, lds + 24576 + q*16384, 1, tid);
    stg(Bg, K2, q*64, lds + 24576 + q*16384, 2, tid);
    stg(Bg, K2, q*64, lds + 24576 + q*16384, 3, tid);
  }

  f32x4 acc[8][4] = {};
  int sRd = 0, sWr = 2;

  for (int q = 0; q < nQ; ++q) {
    const int qs = q + 2 < nQ ? q + 2 : nQ - 1;   // tail: re-stage (unread)
    const char* Asl = lds + sRd*8192;
    const char* Bsl = lds + 24576 + sRd*16384;
    char* AslS = lds + sWr*8192;
    char* BslS = lds + 24576 + sWr*16384;

    asm volatile("s_waitcnt vmcnt(6)" ::: "memory");
    __builtin_amdgcn_s_barrier();
    __builtin_amdgcn_sched_barrier(0);

    bf16x8 af[8], bf[4];
    #pragma unroll
    for (int j = 0; j < 8; j++) af[j] = rdfrag(Asl, j*16 + l15, lq);
    #pragma unroll
    for (int j = 0; j < 4; j++) bf[j] = rdfrag(Bsl, wn*64 + j*16 + l15, lq);
    stg(Ag, K2, qs*64, AslS, 0, tid);
    stg(Ag, K2, qs*64, AslS, 1, tid);
    stg(Bg, K2, qs*64, BslS, 0, tid);
    stg(Bg, K2, qs*64, BslS, 1, tid);
    stg(Bg, K2, qs*64, BslS, 2, tid);
    stg(Bg, K2, qs*64, BslS, 3, tid);
    asm volatile("s_waitcnt lgkmcnt(0)" ::: "memory");
    __builtin_amdgcn_sched_barrier(0);
    __builtin_amdgcn_s_setprio(1);
    #pragma unroll
    for (int mi = 0; mi < 8; mi++)
      #pragma unroll
      for (int ni = 0; ni < 4; ni++)
        acc[mi][ni] = __builtin_amdgcn_mfma_f32_16x16x32_bf16(af[mi], bf[ni], acc[mi][ni], 0, 0, 0);
    __builtin_amdgcn_s_setprio(0);

    sRd = sRd + 1 < 3 ? sRd + 1 : 0;
    sWr = sWr + 1 < 3 ? sWr + 1 : 0;
  }
  asm volatile("s_waitcnt vmcnt(0)" ::: "memory");   // drain tail staging

  if (EPI == 0) {
    #pragma unroll
    for (int mi = 0; mi < 8; mi++) {
      int row = bM*128 + mi*16 + lq*4;
      #pragma unroll
      for (int ni = 0; ni < 4; ni++) {
        int col = bN*256 + wn*64 + ni*16 + l15;
        #pragma unroll
        for (int rr = 0; rr < 4; rr++)
          Cout[(size_t)(row + rr) * N + col] = acc[mi][ni][rr];
      }
    }
  } else {
    // block-uniform segment (0=K,1=V,2=Q) and head (cbase%128 in {0,64})
    const int cbase = bN*256 + wn*64;
    const int seg  = cbase >> 11;
    const int head = (cbase >> 7) & 15;
    #pragma unroll
    for (int mi = 0; mi < 8; mi++) {
      #pragma unroll
      for (int ni = 0; ni < 4; ni++) {
        int col = cbase + ni*16 + l15;
        int d = col & 127;
        float bi = bias[col];
        f32x4 v = acc[mi][ni];
        #pragma unroll
        for (int rr = 0; rr < 4; rr++) {
          int n = bM*128 + mi*16 + lq*4 + rr;   // flat token = t*B + b
          float val = v[rr] + bi;
          int t = n >> 1, b = n & 1;
          int bh = b*NHEAD + head;
          if (seg == 1) {
            Vt[((size_t)bh*HD + d)*T_SEQ + t] = f2bf(val);
          } else {
            // RoPE: reference's flat reshape makes angle row = n % T
            float par = __shfl_xor(val, 1);
            int fidx = d >> 1;
            float cs = cosT[(n & (T_SEQ-1))*64 + fidx];
            float sn = sinT[(n & (T_SEQ-1))*64 + fidx];
            val = (d & 1) ? (par*sn + val*cs) : (val*cs - par*sn);
            val *= SCALE;
            u16* dst = (seg == 0) ? Kh : Qh;
            dst[((size_t)bh*T_SEQ + t)*HD + d] = f2bf(val);
          }
        }
      }
    }
  }
}

// ---------------- causal flash attention, bf16 MFMA ----------------
// 1D grid of 1024 blocks, work-balanced remap: each CU-residue class
// {c, c+256, c+512, c+768} gets qb multiset {b, 31-b, b, 31-b} = 66 tiles.
// LDS exactly 40960B -> 4 blocks/CU, whole grid co-resident, no tail.
__global__ __launch_bounds__(256, 4) void attn_fwd(
    const u16* __restrict__ Qh, const u16* __restrict__ Kh,
    const u16* __restrict__ Vt, u16* __restrict__ O)
{
  const int i = blockIdx.x;
  const int kk = i >> 8, c = i & 255;
  const int bh = (c >> 5) + kk * 8;
  const int b5 = c & 31;
  const int qb = (kk & 1) ? (31 - b5) : b5;

  const int tid = threadIdx.x, lane = tid & 63, w = tid >> 6;
  const int l15 = lane & 15, lq = lane >> 4;

  __shared__ u16 Ks[64*128];      // 16384B, swizzled
  __shared__ u16 Vs[128*64];      // 16384B, swizzled
  __shared__ char Ps[4][2048];    // 8192B: per-wave 16 rows x 128B, XOR-swizzled

  const int q0 = qb*64 + w*16;
  bf16x8 qf[4];
  #pragma unroll
  for (int dc = 0; dc < 4; dc++)
    qf[dc] = *(const bf16x8*)(Qh + ((size_t)bh*T_SEQ + q0 + l15)*HD + dc*32 + lq*8);

  f32x4 o[8] = {};
  float m[4], l_[4];
  #pragma unroll
  for (int r = 0; r < 4; r++) { m[r] = -1e30f; l_[r] = 0.f; }

  const int nkb = qb + 1;
  for (int kb = 0; kb < nkb; ++kb) {
    #pragma unroll
    for (int j = 0; j < 4; j++) {
      int lb = tid*16 + j*4096;
      int row = lb >> 8, bir = lb & 255;
      int sb = bir ^ ((row & 7) << 4);
      gld16((const char*)Kh + (((size_t)bh*T_SEQ + kb*64 + row) << 8) + sb,
            (char*)Ks + lb);
    }
    #pragma unroll
    for (int j = 0; j < 4; j++) {
      int lb = tid*16 + j*4096;
      int row = lb >> 7, bir = lb & 127;
      int sb = bir ^ ((row & 7) << 4);
      gld16((const char*)Vt + ((size_t)(bh*HD + row)*T_SEQ)*2 + kb*128 + sb,
            (char*)Vs + lb);
    }
    __syncthreads();

    // S = Q K^T  (16 q x 64 keys per wave)
    f32x4 sacc[4];
    #pragma unroll
    for (int nf = 0; nf < 4; nf++) {
      f32x4 z = {};
      sacc[nf] = z;
      #pragma unroll
      for (int dc = 0; dc < 4; dc++) {
        int row = nf*16 + l15;
        int bir = (dc*64 + lq*16) ^ ((row & 7) << 4);
        bf16x8 kf = *(const bf16x8*)((const char*)Ks + row*256 + bir);
        sacc[nf] = __builtin_amdgcn_mfma_f32_16x16x32_bf16(qf[dc], kf, sacc[nf], 0, 0, 0);
      }
    }

    if (kb == qb) {   // diagonal block: causal mask
      #pragma unroll
      for (int nf = 0; nf < 4; nf++)
        #pragma unroll
        for (int r = 0; r < 4; r++) {
          int key = kb*64 + nf*16 + l15;
          int qr  = q0 + lq*4 + r;
          if (key > qr) sacc[nf][r] = -1e30f;
        }
    }

    // online softmax (row q = q0+lq*4+r lives in 16 lanes of same lq)
    #pragma unroll
    for (int r = 0; r < 4; r++) {
      float mx = fmaxf(fmaxf(sacc[0][r], sacc[1][r]), fmaxf(sacc[2][r], sacc[3][r]));
      mx = fmaxf(mx, __shfl_xor(mx, 1));
      mx = fmaxf(mx, __shfl_xor(mx, 2));
      mx = fmaxf(mx, __shfl_xor(mx, 4));
      mx = fmaxf(mx, __shfl_xor(mx, 8));
      float newm = fmaxf(m[r], mx);
      float scale = exp2f((m[r] - newm) * LOG2E);
      float sum = 0.f;
      #pragma unroll
      for (int nf = 0; nf < 4; nf++) {
        float p = exp2f((sacc[nf][r] - newm) * LOG2E);
        sacc[nf][r] = p;
        sum += p;
      }
      sum += __shfl_xor(sum, 1);
      sum += __shfl_xor(sum, 2);
      sum += __shfl_xor(sum, 4);
      sum += __shfl_xor(sum, 8);
      l_[r] = l_[r] * scale + sum;
      m[r] = newm;
      #pragma unroll
      for (int nf = 0; nf < 8; nf++) o[nf][r] *= scale;
    }

    // P -> bf16 tile in wave-private LDS slab, XOR-swizzled rows (128B row)
    #pragma unroll
    for (int nf = 0; nf < 4; nf++)
      #pragma unroll
      for (int r = 0; r < 4; r++) {
        int prow = lq*4 + r;
        int pbyte = prow*128 + ((((nf*16 + l15)*2)) ^ ((prow & 7) << 4));
        *(u16*)(Ps[w] + pbyte) = f2bf(sacc[nf][r]);
      }

    // O += P V   (A-frag from Ps, B-frag from swizzled Vs)
    #pragma unroll
    for (int kc = 0; kc < 2; kc++) {
      int pb = (kc*64 + lq*16) ^ ((l15 & 7) << 4);
      bf16x8 pf = *(const bf16x8*)(Ps[w] + l15*128 + pb);
      #pragma unroll
      for (int nf = 0; nf < 8; nf++) {
        int row = nf*16 + l15;
        int bir = (kc*64 + lq*16) ^ ((row & 7) << 4);
        bf16x8 vf = *(const bf16x8*)((const char*)Vs + row*128 + bir);
        o[nf] = __builtin_amdgcn_mfma_f32_16x16x32_bf16(pf, vf, o[nf], 0, 0, 0);
      }
    }
    __syncthreads();
  }

  // epilogue: O row -> [t*B+b][h*D+d] bf16 for the output GEMM
  const int b = bh >> 4, h = bh & 15;
  #pragma unroll
  for (int r = 0; r < 4; r++) {
    float inv = 1.0f / l_[r];
    int t = q0 + lq*4 + r;
    size_t base = ((size_t)(t*2 + b))*EMB + h*HD;
    #pragma unroll
    for (int nf = 0; nf < 8; nf++)
      O[base + nf*16 + l15] = f2bf(o[nf][r] * inv);
  }
}

// ---------------- launch ----------------
extern "C" void kernel_launch(void* const* d_in, const int* in_sizes, int n_in,
                              void* d_out, int out_size, void* d_ws, size_t ws_size,
                              hipStream_t stream) {
  const float* query = (const float*)d_in[0];
  const float* Wqkv  = (const float*)d_in[1];
  const float* bqkv  = (const float*)d_in[2];
  const float* Wo    = (const float*)d_in[3];
  // d_in[4] = bo — reference does NOT add it
  const float* fcos  = (const float*)d_in[5];
  const float* fsin  = (const float*)d_in[6];
  float* out = (float*)d_out;
  char* ws = (char*)d_ws;

  // workspace layout (bytes), total 96MB
  u16* WQb = (u16*)(ws + 0);          // 6144x2048 bf16 = 25165824
  u16* WOb = (u16*)(ws + 25165824);   // 2048x2048 bf16 =  8388608
  u16* A1  = (u16*)(ws + 33554432);   // 4096x2048 bf16 (query; reused as attn out)
  u16* QH  = (u16*)(ws + 50331648);   // [32][2048][128] bf16
  u16* KH  = (u16*)(ws + 67108864);
  u16* VT  = (u16*)(ws + 83886080);   // [32][128][2048] bf16  (end: 100663296)

  cvt_bf16<<<4096, 256, 0, stream>>>(query, A1, 1048576);
  cvt_bf16<<<6144, 256, 0, stream>>>(Wqkv, WQb, 1572864);
  cvt_bf16<<<2048, 256, 0, stream>>>(Wo,   WOb,  524288);

  gemmW<1, 24><<<768, 256, 0, stream>>>(A1, WQb, 2048, NE3,
                                        fcos, fsin, bqkv, QH, KH, VT, nullptr);

  attn_fwd<<<1024, 256, 0, stream>>>(QH, KH, VT, A1);

  gemmW<0, 8><<<256, 256, 0, stream>>>(A1, WOb, 2048, EMB,
                                       nullptr, nullptr, nullptr,
                                       nullptr, nullptr, nullptr, out);
}